// Round 3
// baseline (4425.761 us; speedup 1.0000x reference)
//
#include <hip/hip_runtime.h>
#include <hip/hip_bf16.h>
#include <cstdint>

#define BB 256
#define TT 1024
#define HH 128
#define OO 128
static constexpr long NTOT = (long)BB * TT;

__device__ __forceinline__ float sigmoidf_(float x) { return 1.f / (1.f + expf(-x)); }

// ---------------------------------------------------------------------------
// K1a: x_mean (4-way t-strip parallel) + init carry/hstate.
// grid = B, block = 512 (h, strip).
// carry planes: 0=xlast 1=delta_prev 2=tprev 3=m_prev
// ---------------------------------------------------------------------------
__global__ __launch_bounds__(512) void k1a_mean(
    const float* __restrict__ C, const float* __restrict__ mask,
    float* __restrict__ xmean, float* __restrict__ carry,
    float* __restrict__ hstate) {
  const int b = blockIdx.x;
  const int h = threadIdx.x & (HH - 1);
  const int s = threadIdx.x >> 7;  // 0..3
  __shared__ float ssum[4][HH], scnt[4][HH];
  const float* mptr = mask + (size_t)b * TT * HH + h;
  float sum = 0.f, cnt = 0.f;
  for (int t = s; t < TT; t += 4) {
    float m = mptr[(size_t)t * HH];
    sum = fmaf(m, C[t * HH + h], sum);
    cnt += m;
  }
  ssum[s][h] = sum; scnt[s][h] = cnt;
  __syncthreads();
  if (s == 0) {
    float S = (ssum[0][h] + ssum[1][h]) + (ssum[2][h] + ssum[3][h]);
    float N = (scnt[0][h] + scnt[1][h]) + (scnt[2][h] + scnt[3][h]);
    float xm = S / fmaxf(N, 1.f);
    const size_t bh = (size_t)b * HH + h;
    const size_t BH = (size_t)BB * HH;
    xmean[bh] = xm;
    carry[0 * BH + bh] = xm;
    carry[1 * BH + bh] = 0.f;
    carry[2 * BH + bh] = 0.f;
    carry[3 * BH + bh] = 1.f;
    hstate[bh] = 0.f;
  }
}

// ---------------------------------------------------------------------------
// K1b: per-(b,h) scan for one T-chunk. Writes chunk-local delta/xlastp,
// carries state in ws. grid = B, block = 128.
// ---------------------------------------------------------------------------
__global__ __launch_bounds__(128) void k1b_scan(
    const float* __restrict__ C, const float* __restrict__ tarr,
    const float* __restrict__ mask, float* __restrict__ carry,
    float* __restrict__ delta_c, float* __restrict__ xlastp_c,
    int t0, int TC) {
  const int b = blockIdx.x;
  const int h = threadIdx.x;
  const size_t bh = (size_t)b * HH + h;
  const size_t BH = (size_t)BB * HH;
  float xl = carry[0 * BH + bh];
  float dp = carry[1 * BH + bh];
  float tprev = carry[2 * BH + bh];
  float mp = carry[3 * BH + bh];
  const float* trow = tarr + (size_t)b * TT;
  const float* mptr = mask + ((size_t)b * TT + t0) * HH + h;
  const size_t cbase = (size_t)b * TC * HH + h;
  for (int tl = 0; tl < TC; ++tl) {
    const int t = t0 + tl;
    float tc = trow[t];
    float dt = (t == 0) ? 0.f : (tc - tprev);
    float d = dt + (1.f - mp) * dp;             // mp exactly 0/1
    delta_c[cbase + (size_t)tl * HH] = d;
    xlastp_c[cbase + (size_t)tl * HH] = xl;
    float m = mptr[(size_t)tl * HH];
    float xv = C[t * HH + h];
    xl = m * xv + (1.f - m) * xl;               // m exactly 0/1
    mp = m; dp = d; tprev = tc;
  }
  carry[0 * BH + bh] = xl;
  carry[1 * BH + bh] = dp;
  carry[2 * BH + bh] = tprev;
  carry[3 * BH + bh] = mp;
}

// ---------------------------------------------------------------------------
// K2: fused precompute for one chunk (32-row tiles of (b,t) rows):
//   gx/gh from delta@Wgx/Wgh; x_hat; az/ar/ah = x_hat@W*1 + m@W*3 + b*.
// Streams az|ar|ah|gh into SB[g][4][128] for coalesced K3 reads.
// ---------------------------------------------------------------------------
#define RT2 32
__global__ __launch_bounds__(256) void k2_pre(
    const float* __restrict__ C, const float* __restrict__ mask,
    const float* __restrict__ Wz, const float* __restrict__ bz,
    const float* __restrict__ Wr, const float* __restrict__ br,
    const float* __restrict__ Wh, const float* __restrict__ bh,
    const float* __restrict__ Wgx, const float* __restrict__ bgx,
    const float* __restrict__ Wgh, const float* __restrict__ bgh,
    const float* __restrict__ xmean, const float* __restrict__ delta,
    const float* __restrict__ xlastp, float* __restrict__ SB,
    int t0, int TC, int l2tc) {
  __shared__ float sA[RT2][HH];
  __shared__ float sXh[RT2][HH];
  __shared__ float sM[RT2][HH];
  const int tid = threadIdx.x;
  const long row0 = (long)blockIdx.x * RT2;        // chunk-local row
  const int b = (int)(row0 >> l2tc);
  const int tl0 = (int)(row0 & (TC - 1));
  {
    const float4* gd = (const float4*)(delta + row0 * HH);
    const float4* gm = (const float4*)(mask + ((size_t)b * TT + t0 + tl0) * HH);
    float4* sd = (float4*)&sA[0][0];
    float4* sm = (float4*)&sM[0][0];
    #pragma unroll
    for (int i = 0; i < RT2 * HH / 4 / 256; ++i) {
      sd[tid + i * 256] = gd[tid + i * 256];
      sm[tid + i * 256] = gm[tid + i * 256];
    }
  }
  __syncthreads();
  const int tc = tid & 15, tr = tid >> 4;
  const int j0 = tc * 8, r0 = tr * 2;
  float au[2][8], av[2][8];
  #pragma unroll
  for (int i = 0; i < 2; ++i)
    #pragma unroll
    for (int c = 0; c < 8; ++c) { au[i][c] = 0.f; av[i][c] = 0.f; }
  for (int k = 0; k < HH; ++k) {
    float wu[8], wv[8];
    *(float4*)&wu[0] = *(const float4*)(Wgx + (size_t)k * HH + j0);
    *(float4*)&wu[4] = *(const float4*)(Wgx + (size_t)k * HH + j0 + 4);
    *(float4*)&wv[0] = *(const float4*)(Wgh + (size_t)k * HH + j0);
    *(float4*)&wv[4] = *(const float4*)(Wgh + (size_t)k * HH + j0 + 4);
    #pragma unroll
    for (int i = 0; i < 2; ++i) {
      float a = sA[r0 + i][k];
      #pragma unroll
      for (int c = 0; c < 8; ++c) {
        au[i][c] = fmaf(a, wu[c], au[i][c]);
        av[i][c] = fmaf(a, wv[c], av[i][c]);
      }
    }
  }
  #pragma unroll
  for (int i = 0; i < 2; ++i) {
    const int r = r0 + i;
    const long g = row0 + r;
    const int t = t0 + tl0 + r;
    #pragma unroll
    for (int c = 0; c < 8; ++c) {
      const int j = j0 + c;
      float gx = expf(-fmaxf(au[i][c] + bgx[j], 0.f));
      float gh = expf(-fmaxf(av[i][c] + bgh[j], 0.f));
      float m = sM[r][j];
      float xl = xlastp[g * HH + j];
      float xm = xmean[(size_t)b * HH + j];
      float xv = C[(size_t)t * HH + j];
      float xh = m * xv + (1.f - m) * (gx * xl + (1.f - gx) * xm);
      sXh[r][j] = xh;
      SB[g * 512 + 384 + j] = gh;
    }
  }
  __syncthreads();
  float az[2][8], arr[2][8], ahh[2][8];
  #pragma unroll
  for (int i = 0; i < 2; ++i)
    #pragma unroll
    for (int c = 0; c < 8; ++c) { az[i][c] = 0.f; arr[i][c] = 0.f; ahh[i][c] = 0.f; }
  for (int k = 0; k < HH; ++k) {
    float wz1[8], wz3[8], wr1[8], wr3[8], wh1[8], wh3[8];
    *(float4*)&wz1[0] = *(const float4*)(Wz + (size_t)k * HH + j0);
    *(float4*)&wz1[4] = *(const float4*)(Wz + (size_t)k * HH + j0 + 4);
    *(float4*)&wz3[0] = *(const float4*)(Wz + (size_t)(256 + k) * HH + j0);
    *(float4*)&wz3[4] = *(const float4*)(Wz + (size_t)(256 + k) * HH + j0 + 4);
    *(float4*)&wr1[0] = *(const float4*)(Wr + (size_t)k * HH + j0);
    *(float4*)&wr1[4] = *(const float4*)(Wr + (size_t)k * HH + j0 + 4);
    *(float4*)&wr3[0] = *(const float4*)(Wr + (size_t)(256 + k) * HH + j0);
    *(float4*)&wr3[4] = *(const float4*)(Wr + (size_t)(256 + k) * HH + j0 + 4);
    *(float4*)&wh1[0] = *(const float4*)(Wh + (size_t)k * HH + j0);
    *(float4*)&wh1[4] = *(const float4*)(Wh + (size_t)k * HH + j0 + 4);
    *(float4*)&wh3[0] = *(const float4*)(Wh + (size_t)(256 + k) * HH + j0);
    *(float4*)&wh3[4] = *(const float4*)(Wh + (size_t)(256 + k) * HH + j0 + 4);
    #pragma unroll
    for (int i = 0; i < 2; ++i) {
      float ax = sXh[r0 + i][k], am = sM[r0 + i][k];
      #pragma unroll
      for (int c = 0; c < 8; ++c) {
        az[i][c]  = fmaf(ax, wz1[c], fmaf(am, wz3[c], az[i][c]));
        arr[i][c] = fmaf(ax, wr1[c], fmaf(am, wr3[c], arr[i][c]));
        ahh[i][c] = fmaf(ax, wh1[c], fmaf(am, wh3[c], ahh[i][c]));
      }
    }
  }
  #pragma unroll
  for (int i = 0; i < 2; ++i) {
    const long g = row0 + r0 + i;
    #pragma unroll
    for (int c = 0; c < 8; ++c) {
      const int j = j0 + c;
      SB[g * 512 + j]       = az[i][c] + bz[j];
      SB[g * 512 + 128 + j] = arr[i][c] + br[j];
      SB[g * 512 + 256 + j] = ahh[i][c] + bh[j];
    }
  }
}

// ---------------------------------------------------------------------------
// K3: sequential recurrence over one chunk. One block per batch row,
// 512 threads = (j, q). Thread holds W*2 column slices in 96 VGPRs.
// h persists across chunks via hstate.
// ---------------------------------------------------------------------------
__global__ __launch_bounds__(512) void k3_seq(
    const float* __restrict__ Wz, const float* __restrict__ Wr,
    const float* __restrict__ Wh, const float* __restrict__ SB,
    float* __restrict__ hseq, float* __restrict__ hstate, int TC) {
  const int b = blockIdx.x;
  const int tid = threadIdx.x;
  const int j = tid & (HH - 1);
  const int q = tid >> 7;  // 0:az 1:ar 2:ah 3:gh
  __shared__ float h_s[HH], hdec[HH], rh[HH], zs[HH];
  __shared__ float pz[4][HH], pr[4][HH], ph[4][HH];
  float wz[32], wr[32], wh[32];
  {
    const float* wzp = Wz + (size_t)(HH + 32 * q) * HH + j;
    const float* wrp = Wr + (size_t)(HH + 32 * q) * HH + j;
    const float* whp = Wh + (size_t)(HH + 32 * q) * HH + j;
    #pragma unroll
    for (int i = 0; i < 32; ++i) {
      wz[i] = wzp[i * HH];
      wr[i] = wrp[i * HH];
      wh[i] = whp[i * HH];
    }
  }
  if (tid < HH) h_s[tid] = hstate[(size_t)b * HH + tid];
  const float* sb = SB + (size_t)b * TC * 512 + tid;
  float v0 = sb[0];
  float v1 = sb[512];
  __syncthreads();
  for (int tl = 0; tl < TC; ++tl) {
    const int tn = (tl + 2 < TC) ? (tl + 2) : (TC - 1);
    const float vn = sb[(size_t)tn * 512];
    const float cur = v0;
    if (q == 3) hdec[j] = cur * h_s[j];  // h <- gh * h
    __syncthreads();
    float hq[32];
    {
      const float4* hp = (const float4*)hdec + q * 8;
      #pragma unroll
      for (int i = 0; i < 8; ++i) {
        float4 x = hp[i];
        hq[4*i] = x.x; hq[4*i+1] = x.y; hq[4*i+2] = x.z; hq[4*i+3] = x.w;
      }
    }
    float z0=0.f,z1=0.f,z2=0.f,z3=0.f,s0=0.f,s1=0.f,s2=0.f,s3=0.f;
    #pragma unroll
    for (int i = 0; i < 32; i += 4) {
      z0 = fmaf(hq[i],   wz[i],   z0); s0 = fmaf(hq[i],   wr[i],   s0);
      z1 = fmaf(hq[i+1], wz[i+1], z1); s1 = fmaf(hq[i+1], wr[i+1], s1);
      z2 = fmaf(hq[i+2], wz[i+2], z2); s2 = fmaf(hq[i+2], wr[i+2], s2);
      z3 = fmaf(hq[i+3], wz[i+3], z3); s3 = fmaf(hq[i+3], wr[i+3], s3);
    }
    pz[q][j] = (z0 + z1) + (z2 + z3);
    pr[q][j] = (s0 + s1) + (s2 + s3);
    __syncthreads();
    if (q == 0) {
      zs[j] = sigmoidf_(cur + ((pz[0][j] + pz[1][j]) + (pz[2][j] + pz[3][j])));
    } else if (q == 1) {
      float rv = sigmoidf_(cur + ((pr[0][j] + pr[1][j]) + (pr[2][j] + pr[3][j])));
      rh[j] = rv * hdec[j];
    }
    __syncthreads();
    float rq[32];
    {
      const float4* rp = (const float4*)rh + q * 8;
      #pragma unroll
      for (int i = 0; i < 8; ++i) {
        float4 x = rp[i];
        rq[4*i] = x.x; rq[4*i+1] = x.y; rq[4*i+2] = x.z; rq[4*i+3] = x.w;
      }
    }
    float h0=0.f,h1=0.f,h2=0.f,h3=0.f;
    #pragma unroll
    for (int i = 0; i < 32; i += 4) {
      h0 = fmaf(rq[i],   wh[i],   h0);
      h1 = fmaf(rq[i+1], wh[i+1], h1);
      h2 = fmaf(rq[i+2], wh[i+2], h2);
      h3 = fmaf(rq[i+3], wh[i+3], h3);
    }
    ph[q][j] = (h0 + h1) + (h2 + h3);
    __syncthreads();
    if (q == 2) {
      float ht = tanhf(cur + ((ph[0][j] + ph[1][j]) + (ph[2][j] + ph[3][j])));
      float z = zs[j];
      float hn = (1.f - z) * hdec[j] + z * ht;
      h_s[j] = hn;
      hseq[((size_t)b * TC + tl) * HH + j] = hn;
    }
    __syncthreads();
    v0 = v1; v1 = vn;
  }
  if (tid < HH) hstate[(size_t)b * HH + tid] = h_s[tid];
}

// ---------------------------------------------------------------------------
// K4: out[b, t0+tl, :] = hseq_c @ Wo + bo   (32-row tiles)
// ---------------------------------------------------------------------------
__global__ __launch_bounds__(256) void k4_out(
    const float* __restrict__ hseq, const float* __restrict__ Wo,
    const float* __restrict__ bo, float* __restrict__ out,
    int t0, int TC, int l2tc) {
  __shared__ float sH[32][HH];
  const int tid = threadIdx.x;
  const long row0 = (long)blockIdx.x * 32;
  {
    const float4* gh4 = (const float4*)(hseq + row0 * HH);
    float4* sh4 = (float4*)&sH[0][0];
    #pragma unroll
    for (int i = 0; i < 4; ++i) sh4[tid + i * 256] = gh4[tid + i * 256];
  }
  __syncthreads();
  const int tc = tid & 15, tr = tid >> 4;
  const int j0 = tc * 8, r0 = tr * 2;
  float acc[2][8];
  #pragma unroll
  for (int i = 0; i < 2; ++i)
    #pragma unroll
    for (int c = 0; c < 8; ++c) acc[i][c] = 0.f;
  for (int k = 0; k < HH; ++k) {
    float w[8];
    *(float4*)&w[0] = *(const float4*)(Wo + (size_t)k * HH + j0);
    *(float4*)&w[4] = *(const float4*)(Wo + (size_t)k * HH + j0 + 4);
    #pragma unroll
    for (int i = 0; i < 2; ++i) {
      float a = sH[r0 + i][k];
      #pragma unroll
      for (int c = 0; c < 8; ++c) acc[i][c] = fmaf(a, w[c], acc[i][c]);
    }
  }
  #pragma unroll
  for (int i = 0; i < 2; ++i) {
    const long g = row0 + r0 + i;
    const int b = (int)(g >> l2tc);
    const int tloc = (int)(g & (TC - 1));
    #pragma unroll
    for (int c = 0; c < 8; ++c)
      out[((size_t)b * TT + t0 + tloc) * OO + j0 + c] = acc[i][c] + bo[j0 + c];
  }
}

extern "C" void kernel_launch(void* const* d_in, const int* in_sizes, int n_in,
                              void* d_out, int out_size, void* d_ws, size_t ws_size,
                              hipStream_t stream) {
  const float* C    = (const float*)d_in[0];
  const float* tarr = (const float*)d_in[1];
  const float* mask = (const float*)d_in[2];
  const float* Wz   = (const float*)d_in[3];
  const float* bz   = (const float*)d_in[4];
  const float* Wr   = (const float*)d_in[5];
  const float* br   = (const float*)d_in[6];
  const float* Wh   = (const float*)d_in[7];
  const float* bh   = (const float*)d_in[8];
  const float* Wgx  = (const float*)d_in[9];
  const float* bgx  = (const float*)d_in[10];
  const float* Wgh  = (const float*)d_in[11];
  const float* bgh  = (const float*)d_in[12];
  const float* Wo   = (const float*)d_in[13];
  const float* bo   = (const float*)d_in[14];

  // Pick largest chunk TC that fits ws: floats = 6*B*H + B*TC*(3H + 512)
  int TC = 8, l2tc = 3;
  for (int cand = 1024; cand >= 8; cand >>= 1) {
    size_t need = ((size_t)6 * BB * HH + (size_t)BB * cand * (3 * HH + 512)) * sizeof(float);
    if (need <= ws_size) {
      TC = cand;
      l2tc = 0; while ((1 << l2tc) < cand) ++l2tc;
      break;
    }
  }
  const int NC = TT / TC;

  float* ws = (float*)d_ws;
  const size_t BH = (size_t)BB * HH;
  float* xmean    = ws;                       // B*H
  float* carry    = xmean + BH;               // 4*B*H
  float* hstate   = carry + 4 * BH;           // B*H
  float* delta_c  = hstate + BH;              // B*TC*H
  float* xlastp_c = delta_c + (size_t)BB * TC * HH;
  float* SB_c     = xlastp_c + (size_t)BB * TC * HH;   // B*TC*512
  float* hseq_c   = SB_c + (size_t)BB * TC * 512;      // B*TC*H

  k1a_mean<<<BB, 512, 0, stream>>>(C, mask, xmean, carry, hstate);
  for (int c = 0; c < NC; ++c) {
    const int t0 = c * TC;
    k1b_scan<<<BB, 128, 0, stream>>>(C, tarr, mask, carry, delta_c, xlastp_c, t0, TC);
    k2_pre<<<BB * TC / RT2, 256, 0, stream>>>(C, mask, Wz, bz, Wr, br, Wh, bh,
                                              Wgx, bgx, Wgh, bgh,
                                              xmean, delta_c, xlastp_c, SB_c,
                                              t0, TC, l2tc);
    k3_seq<<<BB, 512, 0, stream>>>(Wz, Wr, Wh, SB_c, hseq_c, hstate, TC);
    k4_out<<<BB * TC / 32, 256, 0, stream>>>(hseq_c, Wo, bo, (float*)d_out, t0, TC, l2tc);
  }
}

// Round 4
// 3020.865 us; speedup vs baseline: 1.4651x; 1.4651x over previous
//
#include <hip/hip_runtime.h>
#include <hip/hip_bf16.h>
#include <cstdint>

#define BB 256
#define TT 1024
#define HH 128
#define OO 128

typedef __attribute__((ext_vector_type(8))) short short8v;
typedef __attribute__((ext_vector_type(4))) float f32x4;

__device__ __forceinline__ float sigmoidf_(float x) { return 1.f / (1.f + expf(-x)); }

__device__ __forceinline__ short f2bf(float x) {
  unsigned u = __float_as_uint(x);
  u = u + 0x7fffu + ((u >> 16) & 1u);
  return (short)(u >> 16);
}
__device__ __forceinline__ float bf2f(short s) {
  return __uint_as_float(((unsigned)(unsigned short)s) << 16);
}
// load 8 consecutive f32 at p, split into hi/lo bf16 fragments
__device__ __forceinline__ void splitA(const float* p, short8v& hi, short8v& lo) {
  float4 a = *(const float4*)p;
  float4 b = *(const float4*)(p + 4);
  float v[8] = {a.x, a.y, a.z, a.w, b.x, b.y, b.z, b.w};
  #pragma unroll
  for (int i = 0; i < 8; ++i) {
    short h = f2bf(v[i]);
    hi[i] = h;
    lo[i] = f2bf(v[i] - bf2f(h));
  }
}

// ---------------------------------------------------------------------------
// K0: weight prep. Convert 8 [128x128] f32 weight blocks to hi/lo bf16 in
// MFMA-B fragment-linear layout: elem e -> i=e&7, lane=(e>>3)&63, tile=e>>9,
// kt=tile>>3, nt=tile&7; k=kt*32+8*(lane>>4)+i, n=nt*16+(lane&15).
// mats: 0=Wgx 1=Wgh 2=Wz1 3=Wz3 4=Wr1 5=Wr3 6=Wh1 7=Wh3
// ---------------------------------------------------------------------------
__global__ __launch_bounds__(256) void k0_wprep(
    const float* __restrict__ Wz, const float* __restrict__ Wr,
    const float* __restrict__ Wh, const float* __restrict__ Wgx,
    const float* __restrict__ Wgh, short* __restrict__ WFRAG) {
  const int mat = blockIdx.x;
  const float* src;
  int koff;
  switch (mat) {
    case 0: src = Wgx; koff = 0; break;
    case 1: src = Wgh; koff = 0; break;
    case 2: src = Wz;  koff = 0; break;
    case 3: src = Wz;  koff = 256; break;
    case 4: src = Wr;  koff = 0; break;
    case 5: src = Wr;  koff = 256; break;
    case 6: src = Wh;  koff = 0; break;
    default: src = Wh; koff = 256; break;
  }
  short* hi = WFRAG + (size_t)mat * 32768;
  short* lo = hi + 16384;
  for (int e = threadIdx.x; e < 16384; e += 256) {
    int i = e & 7, ln = (e >> 3) & 63, tile = e >> 9;
    int kt = tile >> 3, nt = tile & 7;
    int k = kt * 32 + (ln >> 4) * 8 + i;
    int n = nt * 16 + (ln & 15);
    float w = src[(size_t)(koff + k) * HH + n];
    short h = f2bf(w);
    hi[e] = h;
    lo[e] = f2bf(w - bf2f(h));
  }
}

// ---------------------------------------------------------------------------
// K1a: x_mean + init carry/hstate. carry: 0=xlast 1=delta_prev 2=tprev 3=m_prev
// ---------------------------------------------------------------------------
__global__ __launch_bounds__(512) void k1a_mean(
    const float* __restrict__ C, const float* __restrict__ mask,
    float* __restrict__ xmean, float* __restrict__ carry,
    float* __restrict__ hstate) {
  const int b = blockIdx.x;
  const int h = threadIdx.x & (HH - 1);
  const int s = threadIdx.x >> 7;
  __shared__ float ssum[4][HH], scnt[4][HH];
  const float* mptr = mask + (size_t)b * TT * HH + h;
  float sum = 0.f, cnt = 0.f;
  for (int t = s; t < TT; t += 4) {
    float m = mptr[(size_t)t * HH];
    sum = fmaf(m, C[t * HH + h], sum);
    cnt += m;
  }
  ssum[s][h] = sum; scnt[s][h] = cnt;
  __syncthreads();
  if (s == 0) {
    float S = (ssum[0][h] + ssum[1][h]) + (ssum[2][h] + ssum[3][h]);
    float N = (scnt[0][h] + scnt[1][h]) + (scnt[2][h] + scnt[3][h]);
    float xm = S / fmaxf(N, 1.f);
    const size_t bh = (size_t)b * HH + h;
    const size_t BH = (size_t)BB * HH;
    xmean[bh] = xm;
    carry[0 * BH + bh] = xm;
    carry[1 * BH + bh] = 0.f;
    carry[2 * BH + bh] = 0.f;
    carry[3 * BH + bh] = 1.f;
    hstate[bh] = 0.f;
  }
}

// ---------------------------------------------------------------------------
// K1b: per-(b,h) scan for one chunk -> delta_c, xlastp_c (pre-update values)
// ---------------------------------------------------------------------------
__global__ __launch_bounds__(128) void k1b_scan(
    const float* __restrict__ C, const float* __restrict__ tarr,
    const float* __restrict__ mask, float* __restrict__ carry,
    float* __restrict__ delta_c, float* __restrict__ xlastp_c,
    int t0, int TC) {
  const int b = blockIdx.x;
  const int h = threadIdx.x;
  const size_t bh = (size_t)b * HH + h;
  const size_t BH = (size_t)BB * HH;
  float xl = carry[0 * BH + bh];
  float dp = carry[1 * BH + bh];
  float tprev = carry[2 * BH + bh];
  float mp = carry[3 * BH + bh];
  const float* trow = tarr + (size_t)b * TT;
  const float* mptr = mask + ((size_t)b * TT + t0) * HH + h;
  const size_t cbase = (size_t)b * TC * HH + h;
  for (int tl = 0; tl < TC; ++tl) {
    const int t = t0 + tl;
    float tc = trow[t];
    float dt = (t == 0) ? 0.f : (tc - tprev);
    float d = dt + (1.f - mp) * dp;
    delta_c[cbase + (size_t)tl * HH] = d;
    xlastp_c[cbase + (size_t)tl * HH] = xl;
    float m = mptr[(size_t)tl * HH];
    float xv = C[t * HH + h];
    xl = m * xv + (1.f - m) * xl;
    mp = m; dp = d; tprev = tc;
  }
  carry[0 * BH + bh] = xl;
  carry[1 * BH + bh] = dp;
  carry[2 * BH + bh] = tprev;
  carry[3 * BH + bh] = mp;
}

// ---------------------------------------------------------------------------
// K2: split-bf16 MFMA precompute. 128-row tiles, 256 threads = 4 waves,
// wave w owns rows [32w,32w+32) (row-tiles mt=2w+{0,1}).
// Phase A: gx/gh = exp(-relu(delta@Wg* + bg*)); x_hat -> xh_ws (f32).
// Phase B: a{z,r,h} = xh@W*1 + m@W*3 + b*  -> SB streams 0/1/2; gh -> 3.
// Weights staged per-pass into 64KB LDS in fragment-linear layout.
// ---------------------------------------------------------------------------
__global__ __launch_bounds__(256) void k2_mfma(
    const float* __restrict__ C, const float* __restrict__ mask,
    const float* __restrict__ bz, const float* __restrict__ br,
    const float* __restrict__ bh_, const float* __restrict__ bgx,
    const float* __restrict__ bgh, const float* __restrict__ xmean,
    const float* __restrict__ delta, const float* __restrict__ xlastp,
    const short* __restrict__ WFRAG, float* __restrict__ xh_ws,
    float* __restrict__ SB, int t0, int TC, int l2tc) {
  __shared__ short sW[32768];  // 64 KB: [plane 0:hi][plane 1:lo], 16384 each
  const int tid = threadIdx.x;
  const int lane = tid & 63;
  const int wv = tid >> 6;
  const long row0 = (long)blockIdx.x * 128;
  const int lcol = lane & 15;       // n / m within tile
  const int lkg = lane >> 4;        // k-group (A/B frags), row-group (C/D)

  // ---- helpers ----
  #define STAGE(matIdx)                                                      \
    {                                                                        \
      const int4* gsrc = (const int4*)(WFRAG + (size_t)(matIdx) * 32768);    \
      int4* gdst = (int4*)sW;                                                \
      _Pragma("unroll")                                                      \
      for (int i_ = 0; i_ < 16; ++i_) gdst[tid + i_ * 256] = gsrc[tid + i_ * 256]; \
    }
  #define BFRAG(kt, nt, plane) \
    (*(const short8v*)&sW[(plane) * 16384 + (((kt) * 8 + (nt)) * 64 + lane) * 8])

  // ================= Phase A =================
  f32x4 accGX[2][8], accGH[2][8];
  const f32x4 zero4 = {0.f, 0.f, 0.f, 0.f};
  #pragma unroll
  for (int mt = 0; mt < 2; ++mt)
    #pragma unroll
    for (int nt = 0; nt < 8; ++nt) { accGX[mt][nt] = zero4; accGH[mt][nt] = zero4; }

  STAGE(0);  // Wgx
  __syncthreads();
  #pragma unroll
  for (int kt = 0; kt < 4; ++kt) {
    short8v ahi[2], alo[2];
    #pragma unroll
    for (int mt = 0; mt < 2; ++mt) {
      long r = row0 + (wv * 2 + mt) * 16 + lcol;
      splitA(delta + r * HH + kt * 32 + lkg * 8, ahi[mt], alo[mt]);
    }
    #pragma unroll
    for (int nt = 0; nt < 8; ++nt) {
      short8v bhi = BFRAG(kt, nt, 0), blo = BFRAG(kt, nt, 1);
      #pragma unroll
      for (int mt = 0; mt < 2; ++mt) {
        accGX[mt][nt] = __builtin_amdgcn_mfma_f32_16x16x32_bf16(ahi[mt], bhi, accGX[mt][nt], 0, 0, 0);
        accGX[mt][nt] = __builtin_amdgcn_mfma_f32_16x16x32_bf16(ahi[mt], blo, accGX[mt][nt], 0, 0, 0);
        accGX[mt][nt] = __builtin_amdgcn_mfma_f32_16x16x32_bf16(alo[mt], bhi, accGX[mt][nt], 0, 0, 0);
      }
    }
  }
  __syncthreads();
  STAGE(1);  // Wgh
  __syncthreads();
  #pragma unroll
  for (int kt = 0; kt < 4; ++kt) {
    short8v ahi[2], alo[2];
    #pragma unroll
    for (int mt = 0; mt < 2; ++mt) {
      long r = row0 + (wv * 2 + mt) * 16 + lcol;
      splitA(delta + r * HH + kt * 32 + lkg * 8, ahi[mt], alo[mt]);
    }
    #pragma unroll
    for (int nt = 0; nt < 8; ++nt) {
      short8v bhi = BFRAG(kt, nt, 0), blo = BFRAG(kt, nt, 1);
      #pragma unroll
      for (int mt = 0; mt < 2; ++mt) {
        accGH[mt][nt] = __builtin_amdgcn_mfma_f32_16x16x32_bf16(ahi[mt], bhi, accGH[mt][nt], 0, 0, 0);
        accGH[mt][nt] = __builtin_amdgcn_mfma_f32_16x16x32_bf16(ahi[mt], blo, accGH[mt][nt], 0, 0, 0);
        accGH[mt][nt] = __builtin_amdgcn_mfma_f32_16x16x32_bf16(alo[mt], bhi, accGH[mt][nt], 0, 0, 0);
      }
    }
  }
  __syncthreads();

  // elementwise: gh -> SB, x_hat -> xh_ws (f32 row-major)
  #pragma unroll
  for (int mt = 0; mt < 2; ++mt) {
    #pragma unroll
    for (int r = 0; r < 4; ++r) {
      const int mrow = (wv * 2 + mt) * 16 + lkg * 4 + r;
      const long g = row0 + mrow;
      const int b = (int)(g >> l2tc);
      const int tl = (int)(g & (TC - 1));
      const int tg = t0 + tl;
      #pragma unroll
      for (int nt = 0; nt < 8; ++nt) {
        const int j = nt * 16 + lcol;
        float gx = expf(-fmaxf(accGX[mt][nt][r] + bgx[j], 0.f));
        float gh = expf(-fmaxf(accGH[mt][nt][r] + bgh[j], 0.f));
        SB[g * 512 + 384 + j] = gh;
        float mk = mask[((size_t)b * TT + tg) * HH + j];
        float xl = xlastp[g * HH + j];
        float xmn = xmean[(size_t)b * HH + j];
        float xv = C[(size_t)tg * HH + j];
        xh_ws[g * HH + j] = mk * xv + (1.f - mk) * (gx * xl + (1.f - gx) * xmn);
      }
    }
  }
  __threadfence_block();
  __syncthreads();

  // ================= Phase B =================
  // mask fragments (exact bf16), held in regs across the 3 mats
  short8v mfr[2][4];
  #pragma unroll
  for (int mt = 0; mt < 2; ++mt) {
    long r = row0 + (wv * 2 + mt) * 16 + lcol;
    const int b = (int)(r >> l2tc);
    const int tl = (int)(r & (TC - 1));
    const float* mrow = mask + ((size_t)b * TT + t0 + tl) * HH;
    #pragma unroll
    for (int kt = 0; kt < 4; ++kt) {
      float4 p = *(const float4*)(mrow + kt * 32 + lkg * 8);
      float4 q = *(const float4*)(mrow + kt * 32 + lkg * 8 + 4);
      float v[8] = {p.x, p.y, p.z, p.w, q.x, q.y, q.z, q.w};
      #pragma unroll
      for (int i = 0; i < 8; ++i) mfr[mt][kt][i] = f2bf(v[i]);
    }
  }

  #pragma unroll 1
  for (int mat = 0; mat < 3; ++mat) {
    f32x4 acc[2][8];
    #pragma unroll
    for (int mt = 0; mt < 2; ++mt)
      #pragma unroll
      for (int nt = 0; nt < 8; ++nt) acc[mt][nt] = zero4;

    STAGE(2 + mat * 2);  // W*1
    __syncthreads();
    #pragma unroll
    for (int kt = 0; kt < 4; ++kt) {
      short8v ahi[2], alo[2];
      #pragma unroll
      for (int mt = 0; mt < 2; ++mt) {
        long r = row0 + (wv * 2 + mt) * 16 + lcol;
        splitA(xh_ws + r * HH + kt * 32 + lkg * 8, ahi[mt], alo[mt]);
      }
      #pragma unroll
      for (int nt = 0; nt < 8; ++nt) {
        short8v bhi = BFRAG(kt, nt, 0), blo = BFRAG(kt, nt, 1);
        #pragma unroll
        for (int mt = 0; mt < 2; ++mt) {
          acc[mt][nt] = __builtin_amdgcn_mfma_f32_16x16x32_bf16(ahi[mt], bhi, acc[mt][nt], 0, 0, 0);
          acc[mt][nt] = __builtin_amdgcn_mfma_f32_16x16x32_bf16(ahi[mt], blo, acc[mt][nt], 0, 0, 0);
          acc[mt][nt] = __builtin_amdgcn_mfma_f32_16x16x32_bf16(alo[mt], bhi, acc[mt][nt], 0, 0, 0);
        }
      }
    }
    __syncthreads();
    STAGE(3 + mat * 2);  // W*3 (mask side)
    __syncthreads();
    #pragma unroll
    for (int kt = 0; kt < 4; ++kt) {
      #pragma unroll
      for (int nt = 0; nt < 8; ++nt) {
        short8v bhi = BFRAG(kt, nt, 0), blo = BFRAG(kt, nt, 1);
        #pragma unroll
        for (int mt = 0; mt < 2; ++mt) {
          acc[mt][nt] = __builtin_amdgcn_mfma_f32_16x16x32_bf16(mfr[mt][kt], bhi, acc[mt][nt], 0, 0, 0);
          acc[mt][nt] = __builtin_amdgcn_mfma_f32_16x16x32_bf16(mfr[mt][kt], blo, acc[mt][nt], 0, 0, 0);
        }
      }
    }
    __syncthreads();

    const float* bias = (mat == 0) ? bz : (mat == 1) ? br : bh_;
    #pragma unroll
    for (int mt = 0; mt < 2; ++mt) {
      #pragma unroll
      for (int r = 0; r < 4; ++r) {
        const long g = row0 + (wv * 2 + mt) * 16 + lkg * 4 + r;
        #pragma unroll
        for (int nt = 0; nt < 8; ++nt) {
          const int j = nt * 16 + lcol;
          SB[g * 512 + mat * 128 + j] = acc[mt][nt][r] + bias[j];
        }
      }
    }
  }
  #undef STAGE
  #undef BFRAG
}

// ---------------------------------------------------------------------------
// K3: sequential recurrence (unchanged this round). One block per b-row.
// ---------------------------------------------------------------------------
__global__ __launch_bounds__(512) void k3_seq(
    const float* __restrict__ Wz, const float* __restrict__ Wr,
    const float* __restrict__ Wh, const float* __restrict__ SB,
    float* __restrict__ hseq, float* __restrict__ hstate, int TC) {
  const int b = blockIdx.x;
  const int tid = threadIdx.x;
  const int j = tid & (HH - 1);
  const int q = tid >> 7;
  __shared__ float h_s[HH], hdec[HH], rh[HH], zs[HH];
  __shared__ float pz[4][HH], pr[4][HH], ph[4][HH];
  float wz[32], wr[32], wh[32];
  {
    const float* wzp = Wz + (size_t)(HH + 32 * q) * HH + j;
    const float* wrp = Wr + (size_t)(HH + 32 * q) * HH + j;
    const float* whp = Wh + (size_t)(HH + 32 * q) * HH + j;
    #pragma unroll
    for (int i = 0; i < 32; ++i) {
      wz[i] = wzp[i * HH];
      wr[i] = wrp[i * HH];
      wh[i] = whp[i * HH];
    }
  }
  if (tid < HH) h_s[tid] = hstate[(size_t)b * HH + tid];
  const float* sb = SB + (size_t)b * TC * 512 + tid;
  float v0 = sb[0];
  float v1 = sb[512];
  __syncthreads();
  for (int tl = 0; tl < TC; ++tl) {
    const int tn = (tl + 2 < TC) ? (tl + 2) : (TC - 1);
    const float vn = sb[(size_t)tn * 512];
    const float cur = v0;
    if (q == 3) hdec[j] = cur * h_s[j];
    __syncthreads();
    float hq[32];
    {
      const float4* hp = (const float4*)hdec + q * 8;
      #pragma unroll
      for (int i = 0; i < 8; ++i) {
        float4 x = hp[i];
        hq[4*i] = x.x; hq[4*i+1] = x.y; hq[4*i+2] = x.z; hq[4*i+3] = x.w;
      }
    }
    float z0=0.f,z1=0.f,z2=0.f,z3=0.f,s0=0.f,s1=0.f,s2=0.f,s3=0.f;
    #pragma unroll
    for (int i = 0; i < 32; i += 4) {
      z0 = fmaf(hq[i],   wz[i],   z0); s0 = fmaf(hq[i],   wr[i],   s0);
      z1 = fmaf(hq[i+1], wz[i+1], z1); s1 = fmaf(hq[i+1], wr[i+1], s1);
      z2 = fmaf(hq[i+2], wz[i+2], z2); s2 = fmaf(hq[i+2], wr[i+2], s2);
      z3 = fmaf(hq[i+3], wz[i+3], z3); s3 = fmaf(hq[i+3], wr[i+3], s3);
    }
    pz[q][j] = (z0 + z1) + (z2 + z3);
    pr[q][j] = (s0 + s1) + (s2 + s3);
    __syncthreads();
    if (q == 0) {
      zs[j] = sigmoidf_(cur + ((pz[0][j] + pz[1][j]) + (pz[2][j] + pz[3][j])));
    } else if (q == 1) {
      float rv = sigmoidf_(cur + ((pr[0][j] + pr[1][j]) + (pr[2][j] + pr[3][j])));
      rh[j] = rv * hdec[j];
    }
    __syncthreads();
    float rq[32];
    {
      const float4* rp = (const float4*)rh + q * 8;
      #pragma unroll
      for (int i = 0; i < 8; ++i) {
        float4 x = rp[i];
        rq[4*i] = x.x; rq[4*i+1] = x.y; rq[4*i+2] = x.z; rq[4*i+3] = x.w;
      }
    }
    float h0=0.f,h1=0.f,h2=0.f,h3=0.f;
    #pragma unroll
    for (int i = 0; i < 32; i += 4) {
      h0 = fmaf(rq[i],   wh[i],   h0);
      h1 = fmaf(rq[i+1], wh[i+1], h1);
      h2 = fmaf(rq[i+2], wh[i+2], h2);
      h3 = fmaf(rq[i+3], wh[i+3], h3);
    }
    ph[q][j] = (h0 + h1) + (h2 + h3);
    __syncthreads();
    if (q == 2) {
      float ht = tanhf(cur + ((ph[0][j] + ph[1][j]) + (ph[2][j] + ph[3][j])));
      float z = zs[j];
      float hn = (1.f - z) * hdec[j] + z * ht;
      h_s[j] = hn;
      hseq[((size_t)b * TC + tl) * HH + j] = hn;
    }
    __syncthreads();
    v0 = v1; v1 = vn;
  }
  if (tid < HH) hstate[(size_t)b * HH + tid] = h_s[tid];
}

// ---------------------------------------------------------------------------
// K4: out = hseq_c @ Wo + bo
// ---------------------------------------------------------------------------
__global__ __launch_bounds__(256) void k4_out(
    const float* __restrict__ hseq, const float* __restrict__ Wo,
    const float* __restrict__ bo, float* __restrict__ out,
    int t0, int TC, int l2tc) {
  __shared__ float sH[32][HH];
  const int tid = threadIdx.x;
  const long row0 = (long)blockIdx.x * 32;
  {
    const float4* gh4 = (const float4*)(hseq + row0 * HH);
    float4* sh4 = (float4*)&sH[0][0];
    #pragma unroll
    for (int i = 0; i < 4; ++i) sh4[tid + i * 256] = gh4[tid + i * 256];
  }
  __syncthreads();
  const int tc = tid & 15, tr = tid >> 4;
  const int j0 = tc * 8, r0 = tr * 2;
  float acc[2][8];
  #pragma unroll
  for (int i = 0; i < 2; ++i)
    #pragma unroll
    for (int c = 0; c < 8; ++c) acc[i][c] = 0.f;
  for (int k = 0; k < HH; ++k) {
    float w[8];
    *(float4*)&w[0] = *(const float4*)(Wo + (size_t)k * HH + j0);
    *(float4*)&w[4] = *(const float4*)(Wo + (size_t)k * HH + j0 + 4);
    #pragma unroll
    for (int i = 0; i < 2; ++i) {
      float a = sH[r0 + i][k];
      #pragma unroll
      for (int c = 0; c < 8; ++c) acc[i][c] = fmaf(a, w[c], acc[i][c]);
    }
  }
  #pragma unroll
  for (int i = 0; i < 2; ++i) {
    const long g = row0 + r0 + i;
    const int b = (int)(g >> l2tc);
    const int tloc = (int)(g & (TC - 1));
    #pragma unroll
    for (int c = 0; c < 8; ++c)
      out[((size_t)b * TT + t0 + tloc) * OO + j0 + c] = acc[i][c] + bo[j0 + c];
  }
}

extern "C" void kernel_launch(void* const* d_in, const int* in_sizes, int n_in,
                              void* d_out, int out_size, void* d_ws, size_t ws_size,
                              hipStream_t stream) {
  const float* C    = (const float*)d_in[0];
  const float* tarr = (const float*)d_in[1];
  const float* mask = (const float*)d_in[2];
  const float* Wz   = (const float*)d_in[3];
  const float* bz   = (const float*)d_in[4];
  const float* Wr   = (const float*)d_in[5];
  const float* br   = (const float*)d_in[6];
  const float* Wh   = (const float*)d_in[7];
  const float* bh   = (const float*)d_in[8];
  const float* Wgx  = (const float*)d_in[9];
  const float* bgx  = (const float*)d_in[10];
  const float* Wgh  = (const float*)d_in[11];
  const float* bgh  = (const float*)d_in[12];
  const float* Wo   = (const float*)d_in[13];
  const float* bo   = (const float*)d_in[14];

  // ws: [WFRAG 512KB][xmean][carry x4][hstate][delta_c][xlastp_c][SB_c][hseq_c][xh_ws]
  // per-row floats in chunk arrays: delta(128)+xlast(128)+SB(512)+hseq(128)+xh(128) = 1024
  int TC = 8, l2tc = 3;
  for (int cand = 1024; cand >= 8; cand >>= 1) {
    size_t need = 524288 +
        ((size_t)6 * BB * HH + (size_t)BB * cand * 1024) * sizeof(float);
    if (need <= ws_size) {
      TC = cand;
      l2tc = 0; while ((1 << l2tc) < cand) ++l2tc;
      break;
    }
  }
  const int NC = TT / TC;

  short* WFRAG = (short*)d_ws;
  float* fbase = (float*)((char*)d_ws + 524288);
  const size_t BH = (size_t)BB * HH;
  float* xmean    = fbase;
  float* carry    = xmean + BH;
  float* hstate   = carry + 4 * BH;
  float* delta_c  = hstate + BH;
  float* xlastp_c = delta_c + (size_t)BB * TC * HH;
  float* SB_c     = xlastp_c + (size_t)BB * TC * HH;
  float* hseq_c   = SB_c + (size_t)BB * TC * 512;
  float* xh_ws    = hseq_c + (size_t)BB * TC * HH;

  k0_wprep<<<8, 256, 0, stream>>>(Wz, Wr, Wh, Wgx, Wgh, WFRAG);
  k1a_mean<<<BB, 512, 0, stream>>>(C, mask, xmean, carry, hstate);
  for (int c = 0; c < NC; ++c) {
    const int t0 = c * TC;
    k1b_scan<<<BB, 128, 0, stream>>>(C, tarr, mask, carry, delta_c, xlastp_c, t0, TC);
    k2_mfma<<<BB * TC / 128, 256, 0, stream>>>(C, mask, bz, br, bh, bgx, bgh,
                                               xmean, delta_c, xlastp_c,
                                               WFRAG, xh_ws, SB_c, t0, TC, l2tc);
    k3_seq<<<BB, 512, 0, stream>>>(Wz, Wr, Wh, SB_c, hseq_c, hstate, TC);
    k4_out<<<BB * TC / 32, 256, 0, stream>>>(hseq_c, Wo, bo, (float*)d_out, t0, TC, l2tc);
  }
}